// Round 13
// baseline (865.423 us; speedup 1.0000x reference)
//
#include <hip/hip_runtime.h>

#define NT 512   // 8 waves; wave w owns gate-tiles {2w,2w+1} = units 8w..8w+7 (all 4 gates)

typedef _Float16 f16x8 __attribute__((ext_vector_type(8)));
typedef float    f32x4 __attribute__((ext_vector_type(4)));

#define MFMA(a, b, c) __builtin_amdgcn_mfma_f32_16x16x32_f16((a), (b), (c), 0, 0, 0)

#if __has_builtin(__builtin_amdgcn_exp2f)
__device__ __forceinline__ float fexp(float x) { return __builtin_amdgcn_exp2f(x * 1.4426950408889634f); }
#else
__device__ __forceinline__ float fexp(float x) { return __expf(x); }
#endif
#if __has_builtin(__builtin_amdgcn_rcpf)
__device__ __forceinline__ float frcp(float x) { return __builtin_amdgcn_rcpf(x); }
#else
__device__ __forceinline__ float frcp(float x) { return 1.0f / x; }
#endif
__device__ __forceinline__ float sigm(float x)  { return frcp(1.0f + fexp(-x)); }
__device__ __forceinline__ float tanh_(float x) { return 1.0f - 2.0f * frcp(1.0f + fexp(2.0f * x)); }
__device__ __forceinline__ float lrelu(float x) { return x > 0.0f ? x : 0.01f * x; }

__device__ __forceinline__ f16x8 ld8(const float* p) {
    const float4* q = (const float4*)p;
    float4 a = q[0], b = q[1];
    f16x8 r = { (_Float16)a.x, (_Float16)a.y, (_Float16)a.z, (_Float16)a.w,
                (_Float16)b.x, (_Float16)b.y, (_Float16)b.z, (_Float16)b.w };
    return r;
}
__device__ __forceinline__ unsigned pack2(float a, float b) {
    union { _Float16 h[2]; unsigned u; } x;
    x.h[0] = (_Float16)a; x.h[1] = (_Float16)b; return x.u;
}
__device__ __forceinline__ _Float16 half_of(unsigned v, int sel) {
    union { unsigned u; _Float16 h[2]; } x; x.u = v; return x.h[sel];
}

__global__ __launch_bounds__(NT, 2)
void gen_kernel(
    const float* __restrict__ noise,
    const float* __restrict__ w_ih0, const float* __restrict__ w_hh0,
    const float* __restrict__ b_ih0, const float* __restrict__ b_hh0,
    const float* __restrict__ w_ih1, const float* __restrict__ w_hh1,
    const float* __restrict__ b_ih1, const float* __restrict__ b_hh1,
    const float* __restrict__ w_ih2, const float* __restrict__ w_hh2,
    const float* __restrict__ b_ih2, const float* __restrict__ b_hh2,
    const float* __restrict__ fc1_w, const float* __restrict__ fc1_b,
    const float* __restrict__ fc2_w, const float* __restrict__ fc2_b,
    const float* __restrict__ fc3_w, const float* __restrict__ fc3_b,
    const int*   __restrict__ flow_len_p,
    float* __restrict__ out)
{
    // h-state, rotated banking: k-group kg of col c at slot (kg+c)&7, pitch 64.
    // Cols 8-15 dead: zero-initialized, never written.
    __shared__ _Float16 sh[3][2][16 * 64] __attribute__((aligned(16)));  // 12 KB
    __shared__ _Float16 sx[16][40] __attribute__((aligned(16)));

    const int tid  = threadIdx.x;
    const int l    = tid & 63;
    const int w    = tid >> 6;
    const int ls   = l & 15;       // sample col (B/C) == row-in-tile (A)
    const int lj   = l >> 4;       // k-group / C row-group
    const int base = blockIdx.x * 8;
    const int T    = flow_len_p[0];

    // ---------- A fragments ----------
    const int gA  = ls & 3;
    const int rA0 = gA * 64 + 4 * (2 * w + 0) + (ls >> 2);
    const int rA1 = gA * 64 + 4 * (2 * w + 1) + (ls >> 2);

    f16x8 A1[2][4], A2[2][4], A0[2][3];
#pragma unroll
    for (int kc = 0; kc < 2; ++kc) {
        A1[0][kc]     = ld8(w_ih1 + rA0 * 64 + 32 * kc + 8 * lj);
        A1[1][kc]     = ld8(w_ih1 + rA1 * 64 + 32 * kc + 8 * lj);
        A1[0][2 + kc] = ld8(w_hh1 + rA0 * 64 + 32 * kc + 8 * lj);
        A1[1][2 + kc] = ld8(w_hh1 + rA1 * 64 + 32 * kc + 8 * lj);
        A2[0][kc]     = ld8(w_ih2 + rA0 * 64 + 32 * kc + 8 * lj);
        A2[1][kc]     = ld8(w_ih2 + rA1 * 64 + 32 * kc + 8 * lj);
        A2[0][2 + kc] = ld8(w_hh2 + rA0 * 64 + 32 * kc + 8 * lj);
        A2[1][2 + kc] = ld8(w_hh2 + rA1 * 64 + 32 * kc + 8 * lj);
        A0[0][kc]     = ld8(w_hh0 + rA0 * 64 + 32 * kc + 8 * lj);
        A0[1][kc]     = ld8(w_hh0 + rA1 * 64 + 32 * kc + 8 * lj);
    }
#pragma unroll
    for (int tt = 0; tt < 2; ++tt) {
        const int r = tt ? rA1 : rA0;
        f16x8 v;
#pragma unroll
        for (int i = 0; i < 8; ++i) {
            int kl = 8 * lj + i;
            float x = (kl < 3) ? w_ih0[r * 3 + kl]
                    : (kl == 3) ? (b_ih0[r] + b_hh0[r]) : 0.0f;
            v[i] = (_Float16)x;
        }
        A0[tt][2] = v;
    }
    // head A-frags
    f16x8 F1[2][2], F2, F3;
#pragma unroll
    for (int tt = 0; tt < 2; ++tt)
#pragma unroll
        for (int kc = 0; kc < 2; ++kc)
            F1[tt][kc] = ld8(fc1_w + (16 * tt + ls) * 64 + 32 * kc + 8 * lj);
    F2 = ld8(fc2_w + ls * 32 + 8 * lj);
    {
        f16x8 v;
#pragma unroll
        for (int i = 0; i < 8; ++i) {
            int k = 8 * lj + i;
            v[i] = (_Float16)((ls < 3 && k < 16) ? fc3_w[ls * 16 + k] : 0.0f);
        }
        F3 = v;
    }
    // per-lane live cell after repack
    const int uc0 = 8 * w + lj, uc1 = 8 * w + 4 + lj;
    const int u_own = (ls < 8) ? uc0 : uc1;
    const int cs    = ls & 7;
    const int whaddr = cs * 64 + 8 * (((u_own >> 3) + cs) & 7) + (u_own & 7);
    float b1o[4], b2o[4];
#pragma unroll
    for (int g = 0; g < 4; ++g) {
        b1o[g] = b_ih1[g * 64 + u_own] + b_hh1[g * 64 + u_own];
        b2o[g] = b_ih2[g * 64 + u_own] + b_hh2[g * 64 + u_own];
    }
    float hb1a[4], hb1b[4], hb2[4];
#pragma unroll
    for (int r = 0; r < 4; ++r) {
        hb1a[r] = fc1_b[4 * lj + r];
        hb1b[r] = fc1_b[16 + 4 * lj + r];
        hb2[r]  = fc2_b[4 * lj + r];
    }
    float fb3[3] = { fc3_b[0], fc3_b[1], fc3_b[2] };

    // precomputed lane-constant LDS offsets (rotated banking)
    const int colb = ls * 64;
    const int rot0 = colb + 8 * ((lj + ls) & 7);        // k-group lj
    const int rot1 = colb + 8 * ((4 + lj + ls) & 7);    // k-group 4+lj
    const int sxoff = ls * 40 + 8 * lj;
    // head relay lane algebra (R9-verified)
    const int laneA = ls + 32 * (lj & 1);
    const int selH  = lj >> 1;

    // ---------- LDS init ----------
    for (int i = tid; i < 3 * 2 * 16 * 64; i += NT) ((_Float16*)sh)[i] = (_Float16)0.0f;
    for (int i = tid; i < 16 * 40; i += NT) ((_Float16*)sx)[i] = (_Float16)0.0f;
    __syncthreads();
    if (tid < 16) sx[tid][3] = (_Float16)1.0f;
    if (tid < 24) {
        int s = tid / 3, d = tid % 3;
        sx[s][d] = (_Float16)noise[(base + s) * 3 + d];
    }

    float c0s = 0.0f, c1s = 0.0f, c2s = 0.0f;
    const float zb[4] = {0, 0, 0, 0};
    __syncthreads();

#define RDo(L, p, off) (*(const f16x8*)&sh[L][p][off])

#define REPACK(cell, a0, a1)                                                   \
    float cell[4];                                                             \
    _Pragma("unroll")                                                          \
    for (int r = 0; r < 4; ++r) {                                              \
        float v_ = __shfl_xor(a1[r], 8);                                       \
        cell[r] = (ls < 8) ? a0[r] : v_;                                       \
    }

#define ACTC(cell, bo, cref, L, p) {                                           \
        float gi = cell[0] + bo[0], gf = cell[1] + bo[1];                      \
        float gg = cell[2] + bo[2], go = cell[3] + bo[3];                      \
        cref = sigm(gf) * cref + sigm(gi) * tanh_(gg);                         \
        sh[L][p][whaddr] = (_Float16)(sigm(go) * tanh_(cref)); }

    // ---------- prologue: h0(0) from noise ----------
    {
        f16x8 bx = *(const f16x8*)((const _Float16*)sx + sxoff);
        f32x4 a0 = {0, 0, 0, 0}, a1 = {0, 0, 0, 0};
        a0 = MFMA(A0[0][2], bx, a0);
        a1 = MFMA(A0[1][2], bx, a1);
        REPACK(cell, a0, a1)
        ACTC(cell, zb, c0s, 0, 0)
    }
    __syncthreads();
    f16x8 ph1a = RDo(1, 1, rot0), ph1b = RDo(1, 1, rot1);  // zeros

    // ---------- one timestep with compile-time parity PC/PP ----------
#define STEPBODY(PC, PP, tt)                                                   \
    {                                                                          \
        /* I1 */                                                               \
        f16x8 r0 = RDo(0, PC, rot0), r1 = RDo(0, PC, rot1);                    \
        f16x8 nh2a = RDo(2, PP, rot0), nh2b = RDo(2, PP, rot1);                \
        {                                                                      \
            f32x4 a0 = {0, 0, 0, 0}, a1 = {0, 0, 0, 0};                        \
            a0 = MFMA(A1[0][0], r0, a0);   a1 = MFMA(A1[1][0], r0, a1);        \
            a0 = MFMA(A1[0][1], r1, a0);   a1 = MFMA(A1[1][1], r1, a1);        \
            a0 = MFMA(A1[0][2], ph1a, a0); a1 = MFMA(A1[1][2], ph1a, a1);      \
            a0 = MFMA(A1[0][3], ph1b, a0); a1 = MFMA(A1[1][3], ph1b, a1);      \
            REPACK(cell, a0, a1)                                               \
            ACTC(cell, b1o, c1s, 1, PC)                                        \
        }                                                                      \
        __syncthreads();                                                       \
        /* I2 */                                                               \
        {                                                                      \
            f16x8 s0 = RDo(1, PC, rot0), s1 = RDo(1, PC, rot1);                \
            f32x4 a0 = {0, 0, 0, 0}, a1 = {0, 0, 0, 0};                        \
            a0 = MFMA(A2[0][0], s0, a0);   a1 = MFMA(A2[1][0], s0, a1);        \
            a0 = MFMA(A2[0][1], s1, a0);   a1 = MFMA(A2[1][1], s1, a1);        \
            a0 = MFMA(A2[0][2], nh2a, a0); a1 = MFMA(A2[1][2], nh2a, a1);      \
            a0 = MFMA(A2[0][3], nh2b, a0); a1 = MFMA(A2[1][3], nh2b, a1);      \
            REPACK(cell, a0, a1)                                               \
            ACTC(cell, b2o, c2s, 2, PC)                                        \
        }                                                                      \
        __syncthreads();                                                       \
        /* I3: layer0-hh (all waves) || head on wave 0 (shuffle relay) */      \
        f32x4 h0a = {0, 0, 0, 0}, h0b = {0, 0, 0, 0};                          \
        h0a = MFMA(A0[0][0], r0, h0a); h0b = MFMA(A0[1][0], r0, h0b);          \
        h0a = MFMA(A0[0][1], r1, h0a); h0b = MFMA(A0[1][1], r1, h0b);          \
        if (w == 0) {                                                          \
            f16x8 bh0 = RDo(2, PC, rot0), bh1 = RDo(2, PC, rot1);              \
            f32x4 y1a = {0, 0, 0, 0}, y1b = {0, 0, 0, 0};                      \
            y1a = MFMA(F1[0][0], bh0, y1a); y1b = MFMA(F1[1][0], bh0, y1b);    \
            y1a = MFMA(F1[0][1], bh1, y1a); y1b = MFMA(F1[1][1], bh1, y1b);    \
            unsigned pk[4];                                                    \
            _Pragma("unroll")                                                  \
            for (int r = 0; r < 4; ++r)                                        \
                pk[r] = pack2(lrelu(y1a[r] + hb1a[r]),                         \
                              lrelu(y1b[r] + hb1b[r]));                        \
            f16x8 by1;                                                         \
            _Pragma("unroll")                                                  \
            for (int i = 0; i < 4; ++i)                                        \
                by1[i] = half_of((unsigned)__shfl((int)pk[i], laneA), selH);   \
            _Pragma("unroll")                                                  \
            for (int i = 0; i < 4; ++i)                                        \
                by1[4 + i] = half_of((unsigned)__shfl((int)pk[i], laneA + 16), selH); \
            f32x4 y2 = {0, 0, 0, 0};                                           \
            y2 = MFMA(F2, by1, y2);                                            \
            float y2r[4];                                                      \
            _Pragma("unroll")                                                  \
            for (int r = 0; r < 4; ++r) y2r[r] = lrelu(y2[r] + hb2[r]);        \
            f16x8 by2;                                                         \
            _Pragma("unroll")                                                  \
            for (int i = 0; i < 4; ++i) {                                      \
                float v_ = __shfl(y2r[i], laneA);                              \
                by2[i] = (lj < 2) ? (_Float16)v_ : (_Float16)0.0f;             \
            }                                                                  \
            _Pragma("unroll")                                                  \
            for (int i = 0; i < 4; ++i) {                                      \
                float v_ = __shfl(y2r[i], laneA + 16);                         \
                by2[4 + i] = (lj < 2) ? (_Float16)v_ : (_Float16)0.0f;         \
            }                                                                  \
            f32x4 y3 = {0, 0, 0, 0};                                           \
            y3 = MFMA(F3, by2, y3);                                            \
            if (lj == 0) {                                                     \
                float o0 = lrelu(y3[0] + fb3[0]);                              \
                float o1 = lrelu(y3[1] + fb3[1]);                              \
                float o2 = lrelu(y3[2] + fb3[2]);                              \
                sx[ls][0] = (_Float16)o0;                                      \
                sx[ls][1] = (_Float16)o1;                                      \
                sx[ls][2] = (_Float16)o2;                                      \
                if (ls < 8) {                                                  \
                    float* op = out + ((size_t)(base + ls) * T + (tt)) * 3;    \
                    op[0] = o0; op[1] = o1; op[2] = o2;                        \
                }                                                              \
            }                                                                  \
        }                                                                      \
        __syncthreads();                                                       \
        /* I4 */                                                               \
        {                                                                      \
            f16x8 bx = *(const f16x8*)((const _Float16*)sx + sxoff);           \
            h0a = MFMA(A0[0][2], bx, h0a);                                     \
            h0b = MFMA(A0[1][2], bx, h0b);                                     \
            REPACK(cell, h0a, h0b)                                             \
            ACTC(cell, zb, c0s, 0, PP)                                         \
        }                                                                      \
        ph1a = RDo(1, PC, rot0); ph1b = RDo(1, PC, rot1);                      \
        __syncthreads();                                                       \
    }

    // ---------- time loop: 2x unrolled, parity compile-time ----------
    for (int t = 0; t < T; t += 2) {
        STEPBODY(0, 1, t)
        if (t + 1 < T) {
            STEPBODY(1, 0, t + 1)
        }
    }
}

extern "C" void kernel_launch(void* const* d_in, const int* in_sizes, int n_in,
                              void* d_out, int out_size, void* d_ws, size_t ws_size,
                              hipStream_t stream) {
    const float* noise = (const float*)d_in[0];
    const float* w_ih0 = (const float*)d_in[1];
    const float* w_hh0 = (const float*)d_in[2];
    const float* b_ih0 = (const float*)d_in[3];
    const float* b_hh0 = (const float*)d_in[4];
    const float* w_ih1 = (const float*)d_in[5];
    const float* w_hh1 = (const float*)d_in[6];
    const float* b_ih1 = (const float*)d_in[7];
    const float* b_hh1 = (const float*)d_in[8];
    const float* w_ih2 = (const float*)d_in[9];
    const float* w_hh2 = (const float*)d_in[10];
    const float* b_ih2 = (const float*)d_in[11];
    const float* b_hh2 = (const float*)d_in[12];
    const float* fc1w  = (const float*)d_in[13];
    const float* fc1b  = (const float*)d_in[14];
    const float* fc2w  = (const float*)d_in[15];
    const float* fc2b  = (const float*)d_in[16];
    const float* fc3w  = (const float*)d_in[17];
    const float* fc3b  = (const float*)d_in[18];
    const int*   flp   = (const int*)d_in[19];

    gen_kernel<<<dim3(256), dim3(NT), 0, stream>>>(
        noise, w_ih0, w_hh0, b_ih0, b_hh0,
        w_ih1, w_hh1, b_ih1, b_hh1,
        w_ih2, w_hh2, b_ih2, b_hh2,
        fc1w, fc1b, fc2w, fc2b, fc3w, fc3b,
        flp, (float*)d_out);
}

// Round 14
// 809.672 us; speedup vs baseline: 1.0689x; 1.0689x over previous
//
#include <hip/hip_runtime.h>

#define NT 512   // 8 waves; wave w owns gate-tiles {2w,2w+1} = units 8w..8w+7 (all 4 gates)

typedef _Float16 f16x8 __attribute__((ext_vector_type(8)));
typedef _Float16 f16x4 __attribute__((ext_vector_type(4)));
typedef float    f32x4 __attribute__((ext_vector_type(4)));

#define MFMA(a, b, c) __builtin_amdgcn_mfma_f32_16x16x32_f16((a), (b), (c), 0, 0, 0)

#if __has_builtin(__builtin_amdgcn_exp2f)
__device__ __forceinline__ float fexp(float x) { return __builtin_amdgcn_exp2f(x * 1.4426950408889634f); }
#else
__device__ __forceinline__ float fexp(float x) { return __expf(x); }
#endif
#if __has_builtin(__builtin_amdgcn_rcpf)
__device__ __forceinline__ float frcp(float x) { return __builtin_amdgcn_rcpf(x); }
#else
__device__ __forceinline__ float frcp(float x) { return 1.0f / x; }
#endif
__device__ __forceinline__ float sigm(float x)  { return frcp(1.0f + fexp(-x)); }
__device__ __forceinline__ float tanh_(float x) { return 1.0f - 2.0f * frcp(1.0f + fexp(2.0f * x)); }
__device__ __forceinline__ float lrelu(float x) { return x > 0.0f ? x : 0.01f * x; }

__device__ __forceinline__ f16x8 ld8(const float* p) {
    const float4* q = (const float4*)p;
    float4 a = q[0], b = q[1];
    f16x8 r = { (_Float16)a.x, (_Float16)a.y, (_Float16)a.z, (_Float16)a.w,
                (_Float16)b.x, (_Float16)b.y, (_Float16)b.z, (_Float16)b.w };
    return r;
}

__global__ __launch_bounds__(NT, 2)
void gen_kernel(
    const float* __restrict__ noise,
    const float* __restrict__ w_ih0, const float* __restrict__ w_hh0,
    const float* __restrict__ b_ih0, const float* __restrict__ b_hh0,
    const float* __restrict__ w_ih1, const float* __restrict__ w_hh1,
    const float* __restrict__ b_ih1, const float* __restrict__ b_hh1,
    const float* __restrict__ w_ih2, const float* __restrict__ w_hh2,
    const float* __restrict__ b_ih2, const float* __restrict__ b_hh2,
    const float* __restrict__ fc1_w, const float* __restrict__ fc1_b,
    const float* __restrict__ fc2_w, const float* __restrict__ fc2_b,
    const float* __restrict__ fc3_w, const float* __restrict__ fc3_b,
    const int*   __restrict__ flow_len_p,
    float* __restrict__ out)
{
    // h-state, rotated banking (R11): k-group kg of col c stored at slot (kg+c)&7.
    // Cols 8-15 are dead samples: zero-initialized and NEVER written (repack).
    __shared__ _Float16 sh[3][2][16 * 64] __attribute__((aligned(16)));  // 12 KB
    __shared__ _Float16 sx [16][40] __attribute__((aligned(16)));
    __shared__ _Float16 sy1[16][40] __attribute__((aligned(16)));
    __shared__ _Float16 sy2[16][40] __attribute__((aligned(16)));
    __shared__ float4   stage[8][8];   // [sample][step&7] -> {o0,o1,o2,pad}, 1 KB

    const int tid  = threadIdx.x;
    const int l    = tid & 63;
    const int w    = tid >> 6;     // wave 0..7
    const int ls   = l & 15;       // sample col (B/C) == row-in-tile (A)
    const int lj   = l >> 4;       // k-group / C row-group
    const int base = blockIdx.x * 8;
    const int T    = flow_len_p[0];

    // ---------- A fragments ----------
    const int gA  = ls & 3;
    const int rA0 = gA * 64 + 4 * (2 * w + 0) + (ls >> 2);
    const int rA1 = gA * 64 + 4 * (2 * w + 1) + (ls >> 2);

    f16x8 A1[2][4], A2[2][4], A0[2][3];
#pragma unroll
    for (int kc = 0; kc < 2; ++kc) {
        A1[0][kc]     = ld8(w_ih1 + rA0 * 64 + 32 * kc + 8 * lj);
        A1[1][kc]     = ld8(w_ih1 + rA1 * 64 + 32 * kc + 8 * lj);
        A1[0][2 + kc] = ld8(w_hh1 + rA0 * 64 + 32 * kc + 8 * lj);
        A1[1][2 + kc] = ld8(w_hh1 + rA1 * 64 + 32 * kc + 8 * lj);
        A2[0][kc]     = ld8(w_ih2 + rA0 * 64 + 32 * kc + 8 * lj);
        A2[1][kc]     = ld8(w_ih2 + rA1 * 64 + 32 * kc + 8 * lj);
        A2[0][2 + kc] = ld8(w_hh2 + rA0 * 64 + 32 * kc + 8 * lj);
        A2[1][2 + kc] = ld8(w_hh2 + rA1 * 64 + 32 * kc + 8 * lj);
        A0[0][kc]     = ld8(w_hh0 + rA0 * 64 + 32 * kc + 8 * lj);
        A0[1][kc]     = ld8(w_hh0 + rA1 * 64 + 32 * kc + 8 * lj);
    }
#pragma unroll
    for (int tt = 0; tt < 2; ++tt) {
        const int r = tt ? rA1 : rA0;
        f16x8 v;
#pragma unroll
        for (int i = 0; i < 8; ++i) {
            int kl = 8 * lj + i;
            float x = (kl < 3) ? w_ih0[r * 3 + kl]
                    : (kl == 3) ? (b_ih0[r] + b_hh0[r]) : 0.0f;
            v[i] = (_Float16)x;
        }
        A0[tt][2] = v;
    }
    // head A-frags (wave 0 uses them)
    f16x8 F1[2][2], F2, F3;
#pragma unroll
    for (int tt = 0; tt < 2; ++tt)
#pragma unroll
        for (int kc = 0; kc < 2; ++kc)
            F1[tt][kc] = ld8(fc1_w + (16 * tt + ls) * 64 + 32 * kc + 8 * lj);
    F2 = ld8(fc2_w + ls * 32 + 8 * lj);
    {
        f16x8 v;
#pragma unroll
        for (int i = 0; i < 8; ++i) {
            int k = 8 * lj + i;
            v[i] = (_Float16)((ls < 3 && k < 16) ? fc3_w[ls * 16 + k] : 0.0f);
        }
        F3 = v;
    }
    // per-lane live cell after repack: unit u_own, col cs
    const int uc0 = 8 * w + lj, uc1 = 8 * w + 4 + lj;
    const int u_own = (ls < 8) ? uc0 : uc1;
    const int cs    = ls & 7;
    const int whaddr = cs * 64 + 8 * (((u_own >> 3) + cs) & 7) + (u_own & 7);
    float b1o[4], b2o[4];
#pragma unroll
    for (int g = 0; g < 4; ++g) {
        b1o[g] = b_ih1[g * 64 + u_own] + b_hh1[g * 64 + u_own];
        b2o[g] = b_ih2[g * 64 + u_own] + b_hh2[g * 64 + u_own];
    }
    float hb1a[4], hb1b[4], hb2[4];
#pragma unroll
    for (int r = 0; r < 4; ++r) {
        hb1a[r] = fc1_b[4 * lj + r];
        hb1b[r] = fc1_b[16 + 4 * lj + r];
        hb2[r]  = fc2_b[4 * lj + r];
    }
    float fb3[3] = { fc3_b[0], fc3_b[1], fc3_b[2] };

    // ---------- LDS init ----------
    for (int i = tid; i < 3 * 2 * 16 * 64; i += NT) ((_Float16*)sh)[i] = (_Float16)0.0f;
    for (int i = tid; i < 16 * 40; i += NT) {
        ((_Float16*)sx)[i]  = (_Float16)0.0f;
        ((_Float16*)sy1)[i] = (_Float16)0.0f;
        ((_Float16*)sy2)[i] = (_Float16)0.0f;
    }
    __syncthreads();
    if (tid < 16) sx[tid][3] = (_Float16)1.0f;
    if (tid < 24) {
        int s = tid / 3, d = tid % 3;
        sx[s][d] = (_Float16)noise[(base + s) * 3 + d];
    }

    float c0s = 0.0f, c1s = 0.0f, c2s = 0.0f;
    const float zb[4] = {0, 0, 0, 0};
    __syncthreads();

#define RD(L, p, kg) (*(const f16x8*)&sh[L][p][ls * 64 + 8 * (((kg) + ls) & 7)])

#define REPACK(cell, a0, a1)                                                   \
    float cell[4];                                                             \
    _Pragma("unroll")                                                          \
    for (int r = 0; r < 4; ++r) {                                              \
        float v_ = __shfl_xor(a1[r], 8);                                       \
        cell[r] = (ls < 8) ? a0[r] : v_;                                       \
    }

#define ACTC(cell, bo, cref, L, p) {                                           \
        float gi = cell[0] + bo[0], gf = cell[1] + bo[1];                      \
        float gg = cell[2] + bo[2], go = cell[3] + bo[3];                      \
        cref = sigm(gf) * cref + sigm(gi) * tanh_(gg);                         \
        sh[L][p][whaddr] = (_Float16)(sigm(go) * tanh_(cref)); }

    // flush CNT staged steps ending at T-1 (or 8 ending at t-1): wave 1 only,
    // 3 dword stores/lane, coalesced in 24-float runs. t0 is always %8==0.
#define FLUSH(t0, CNT) {                                                       \
        _Pragma("unroll")                                                      \
        for (int r_ = 0; r_ < 3; ++r_) {                                       \
            int f_ = l + 64 * r_;            /* 0..191 */                      \
            int s_ = f_ / 24, rem_ = f_ % 24;                                  \
            int k_ = rem_ / 3;                                                 \
            if (k_ < (CNT)) {                                                  \
                const float* st_ = (const float*)&stage[s_][k_];               \
                out[((size_t)(base + s_) * T + (t0)) * 3 + rem_] =             \
                    st_[rem_ % 3];                                             \
            }                                                                  \
        }                                                                      \
    }

    // ---------- prologue: h0(0) from noise ----------
    {
        f16x8 bx = *(const f16x8*)&sx[ls][8 * lj];
        f32x4 a0 = {0, 0, 0, 0}, a1 = {0, 0, 0, 0};
        a0 = MFMA(A0[0][2], bx, a0);
        a1 = MFMA(A0[1][2], bx, a1);
        REPACK(cell, a0, a1)
        ACTC(cell, zb, c0s, 0, 0)
    }
    __syncthreads();
    f16x8 ph1a = RD(1, 1, lj), ph1b = RD(1, 1, 4 + lj);  // zeros

    // ---------- time loop: 4 barriers/step ----------
    for (int t = 0; t < T; ++t) {
        const int pc = t & 1, pp = pc ^ 1;
        // I1: gates1 = [Wi1|Wh1]·[h0(pc); h1(pp)] -> ACT1 -> h1(pc)
        f16x8 r0 = RD(0, pc, lj), r1 = RD(0, pc, 4 + lj);
        f16x8 nh2a = RD(2, pp, lj), nh2b = RD(2, pp, 4 + lj);   // hoist for I2
        {
            f32x4 a0 = {0, 0, 0, 0}, a1 = {0, 0, 0, 0};
            a0 = MFMA(A1[0][0], r0, a0);   a1 = MFMA(A1[1][0], r0, a1);
            a0 = MFMA(A1[0][1], r1, a0);   a1 = MFMA(A1[1][1], r1, a1);
            a0 = MFMA(A1[0][2], ph1a, a0); a1 = MFMA(A1[1][2], ph1a, a1);
            a0 = MFMA(A1[0][3], ph1b, a0); a1 = MFMA(A1[1][3], ph1b, a1);
            REPACK(cell, a0, a1)
            ACTC(cell, b1o, c1s, 1, pc)
        }
        __syncthreads();
        // I2: gates2 = [Wi2|Wh2]·[h1(pc); h2(pp)] -> ACT2 -> h2(pc)
        {
            f16x8 s0 = RD(1, pc, lj), s1 = RD(1, pc, 4 + lj);
            f32x4 a0 = {0, 0, 0, 0}, a1 = {0, 0, 0, 0};
            a0 = MFMA(A2[0][0], s0, a0);   a1 = MFMA(A2[1][0], s0, a1);
            a0 = MFMA(A2[0][1], s1, a0);   a1 = MFMA(A2[1][1], s1, a1);
            a0 = MFMA(A2[0][2], nh2a, a0); a1 = MFMA(A2[1][2], nh2a, a1);
            a0 = MFMA(A2[0][3], nh2b, a0); a1 = MFMA(A2[1][3], nh2b, a1);
            REPACK(cell, a0, a1)
            ACTC(cell, b2o, c2s, 2, pc)
        }
        __syncthreads();
        // I3: layer0-hh from register-held r0,r1 (acc to I4)
        //     || head on wave 0 (stores y3 to LDS stage, NOT global)
        //     || wave 1: flush previous 8 staged steps every 8th step
        f32x4 h0a = {0, 0, 0, 0}, h0b = {0, 0, 0, 0};
        h0a = MFMA(A0[0][0], r0, h0a); h0b = MFMA(A0[1][0], r0, h0b);
        h0a = MFMA(A0[0][1], r1, h0a); h0b = MFMA(A0[1][1], r1, h0b);
        if (w == 0) {
            f16x8 bh0 = RD(2, pc, lj), bh1 = RD(2, pc, 4 + lj);
            f32x4 y1a = {0, 0, 0, 0}, y1b = {0, 0, 0, 0};
            y1a = MFMA(F1[0][0], bh0, y1a); y1b = MFMA(F1[1][0], bh0, y1b);
            y1a = MFMA(F1[0][1], bh1, y1a); y1b = MFMA(F1[1][1], bh1, y1b);
            f16x4 v;
#pragma unroll
            for (int r = 0; r < 4; ++r) v[r] = (_Float16)lrelu(y1a[r] + hb1a[r]);
            *(f16x4*)&sy1[ls][4 * lj] = v;
#pragma unroll
            for (int r = 0; r < 4; ++r) v[r] = (_Float16)lrelu(y1b[r] + hb1b[r]);
            *(f16x4*)&sy1[ls][16 + 4 * lj] = v;
            f16x8 by1 = *(const f16x8*)&sy1[ls][8 * lj];
            f32x4 y2 = {0, 0, 0, 0};
            y2 = MFMA(F2, by1, y2);
#pragma unroll
            for (int r = 0; r < 4; ++r) v[r] = (_Float16)lrelu(y2[r] + hb2[r]);
            *(f16x4*)&sy2[ls][4 * lj] = v;
            f16x8 by2 = *(const f16x8*)&sy2[ls][8 * lj];
            f32x4 y3 = {0, 0, 0, 0};
            y3 = MFMA(F3, by2, y3);
            if (lj == 0) {
                float o0 = lrelu(y3[0] + fb3[0]);
                float o1 = lrelu(y3[1] + fb3[1]);
                float o2 = lrelu(y3[2] + fb3[2]);
                sx[ls][0] = (_Float16)o0;
                sx[ls][1] = (_Float16)o1;
                sx[ls][2] = (_Float16)o2;
                if (ls < 8) stage[ls][t & 7] = make_float4(o0, o1, o2, 0.0f);
            }
        }
        if (w == 1 && t > 0 && (t & 7) == 0) FLUSH(t - 8, 8)
        __syncthreads();
        // I4: gates0 += Wi0p·[y3;1;0..] -> ACT0 -> h0(pp)
        {
            f16x8 bx = *(const f16x8*)&sx[ls][8 * lj];
            h0a = MFMA(A0[0][2], bx, h0a);
            h0b = MFMA(A0[1][2], bx, h0b);
            REPACK(cell, h0a, h0b)
            ACTC(cell, zb, c0s, 0, pp)
        }
        ph1a = RD(1, pc, lj); ph1b = RD(1, pc, 4 + lj);  // hoist for next I1
        __syncthreads();
    }
    // final flush: CNT = ((T-1)&7)+1 staged steps ending at T-1 (t0 %8 == 0)
    {
        const int cnt = ((T - 1) & 7) + 1;
        const int t0  = T - cnt;
        if (w == 1) FLUSH(t0, cnt)
    }
}

extern "C" void kernel_launch(void* const* d_in, const int* in_sizes, int n_in,
                              void* d_out, int out_size, void* d_ws, size_t ws_size,
                              hipStream_t stream) {
    const float* noise = (const float*)d_in[0];
    const float* w_ih0 = (const float*)d_in[1];
    const float* w_hh0 = (const float*)d_in[2];
    const float* b_ih0 = (const float*)d_in[3];
    const float* b_hh0 = (const float*)d_in[4];
    const float* w_ih1 = (const float*)d_in[5];
    const float* w_hh1 = (const float*)d_in[6];
    const float* b_ih1 = (const float*)d_in[7];
    const float* b_hh1 = (const float*)d_in[8];
    const float* w_ih2 = (const float*)d_in[9];
    const float* w_hh2 = (const float*)d_in[10];
    const float* b_ih2 = (const float*)d_in[11];
    const float* b_hh2 = (const float*)d_in[12];
    const float* fc1w  = (const float*)d_in[13];
    const float* fc1b  = (const float*)d_in[14];
    const float* fc2w  = (const float*)d_in[15];
    const float* fc2b  = (const float*)d_in[16];
    const float* fc3w  = (const float*)d_in[17];
    const float* fc3b  = (const float*)d_in[18];
    const int*   flp   = (const int*)d_in[19];

    gen_kernel<<<dim3(256), dim3(NT), 0, stream>>>(
        noise, w_ih0, w_hh0, b_ih0, b_hh0,
        w_ih1, w_hh1, b_ih1, b_hh1,
        w_ih2, w_hh2, b_ih2, b_hh2,
        fc1w, fc1b, fc2w, fc2b, fc3w, fc3b,
        flp, (float*)d_out);
}